// Round 2
// baseline (305.797 us; speedup 1.0000x reference)
//
#include <hip/hip_runtime.h>
#include <math.h>

#define N_NODES 32768
#define HC 256
#define NPG 512
#define NGRAPH 64
#define KKEEP 256
#define CAP 64

// ---------------- GEMM: h = x @ W, fused a_src/a_dst ----------------
__global__ __launch_bounds__(256) void k_gemm(
    const float* __restrict__ x, const float* __restrict__ W,
    const float* __restrict__ attS, const float* __restrict__ attD,
    float* __restrict__ h, float* __restrict__ a_src, float* __restrict__ a_dst) {
  __shared__ float xs[64][36];
  __shared__ float ws[32][256];
  const int t = threadIdx.x;
  const int ty = t >> 6;
  const int tx = t & 63;
  const int row0 = blockIdx.x * 64;
  const int c0 = tx * 4;
  float4 acc[16];
#pragma unroll
  for (int i = 0; i < 16; i++) acc[i] = make_float4(0.f, 0.f, 0.f, 0.f);

  for (int k0 = 0; k0 < 256; k0 += 32) {
    {
      int r = t >> 3, f = t & 7;
      const float4* s1 = (const float4*)&x[(size_t)(row0 + r) * 256 + k0];
      *(float4*)&xs[r][f * 4] = s1[f];
      const float4* s2 = (const float4*)&x[(size_t)(row0 + r + 32) * 256 + k0];
      *(float4*)&xs[r + 32][f * 4] = s2[f];
    }
#pragma unroll
    for (int m = 0; m < 8; m++) {
      int idx = m * 256 + t;
      int kr = idx >> 6, f4 = (idx & 63) * 4;
      *(float4*)&ws[kr][f4] = *(const float4*)&W[(size_t)(k0 + kr) * 256 + f4];
    }
    __syncthreads();
#pragma unroll
    for (int kk = 0; kk < 32; kk += 4) {
      float4 wv0 = *(float4*)&ws[kk + 0][c0];
      float4 wv1 = *(float4*)&ws[kk + 1][c0];
      float4 wv2 = *(float4*)&ws[kk + 2][c0];
      float4 wv3 = *(float4*)&ws[kk + 3][c0];
#pragma unroll
      for (int i = 0; i < 16; i++) {
        float4 xv = *(float4*)&xs[ty * 16 + i][kk];
        float4 a = acc[i];
        a.x = fmaf(xv.w, wv3.x, fmaf(xv.z, wv2.x, fmaf(xv.y, wv1.x, fmaf(xv.x, wv0.x, a.x))));
        a.y = fmaf(xv.w, wv3.y, fmaf(xv.z, wv2.y, fmaf(xv.y, wv1.y, fmaf(xv.x, wv0.y, a.y))));
        a.z = fmaf(xv.w, wv3.z, fmaf(xv.z, wv2.z, fmaf(xv.y, wv1.z, fmaf(xv.x, wv0.z, a.z))));
        a.w = fmaf(xv.w, wv3.w, fmaf(xv.z, wv2.w, fmaf(xv.y, wv1.w, fmaf(xv.x, wv0.w, a.w))));
        acc[i] = a;
      }
    }
    __syncthreads();
  }
  const float4 aS = *(const float4*)&attS[c0];
  const float4 aD = *(const float4*)&attD[c0];
  const int head = tx >> 4;
#pragma unroll
  for (int i = 0; i < 16; i++) {
    int r = row0 + ty * 16 + i;
    *(float4*)&h[(size_t)r * 256 + c0] = acc[i];
    float ps = acc[i].x * aS.x + acc[i].y * aS.y + acc[i].z * aS.z + acc[i].w * aS.w;
    float pd = acc[i].x * aD.x + acc[i].y * aD.y + acc[i].z * aD.z + acc[i].w * aD.w;
#pragma unroll
    for (int d = 1; d < 16; d <<= 1) {
      ps += __shfl_xor(ps, d, 16);
      pd += __shfl_xor(pd, d, 16);
    }
    if ((tx & 15) == 0) {
      a_src[r * 4 + head] = ps;
      a_dst[r * 4 + head] = pd;
    }
  }
}

// ---------------- edge bucketing by dst (local ushort indices) ----------------
__global__ void k_hist(const int* __restrict__ ei, int E, int* __restrict__ cnt,
                       unsigned short* __restrict__ nbr) {
  int e = blockIdx.x * 256 + threadIdx.x;
  if (e < E) {
    int s = ei[e];
    int d = ei[E + e];
    int slot = atomicAdd(&cnt[d], 1);
    if (slot < CAP) nbr[(size_t)d * CAP + slot] = (unsigned short)(s & (NPG - 1));
  }
}

// ---------------- softmax stats per node: m, 1/l per head ----------------
// one wave per node; lanes parallel over edges, shuffle-reduce
__global__ __launch_bounds__(256) void k_soft(
    const float* __restrict__ a_src, const float* __restrict__ a_dst,
    const int* __restrict__ cnt, const unsigned short* __restrict__ nbr,
    float* __restrict__ m_arr, float* __restrict__ linv_arr) {
  const int lane = threadIdx.x & 63;
  int nb = (blockIdx.x & 7) * (N_NODES / 4 / 8) + (blockIdx.x >> 3);
  const int node = nb * 4 + (threadIdx.x >> 6);
  const int base = node & ~(NPG - 1);
  int n = cnt[node];
  if (n > CAP) n = CAP;
  const float4 ad = *(const float4*)&a_dst[node * 4];
  float4 items[2];
  int nit = 0;
  float4 m = make_float4(-1e30f, -1e30f, -1e30f, -1e30f);
  for (int j = lane; j <= n; j += 64) {
    int src = (j < n) ? base + (int)nbr[(size_t)node * CAP + j] : node;
    float4 as = *(const float4*)&a_src[src * 4];
    float4 e;
    e.x = as.x + ad.x; e.x = (e.x > 0.f) ? e.x : 0.2f * e.x;
    e.y = as.y + ad.y; e.y = (e.y > 0.f) ? e.y : 0.2f * e.y;
    e.z = as.z + ad.z; e.z = (e.z > 0.f) ? e.z : 0.2f * e.z;
    e.w = as.w + ad.w; e.w = (e.w > 0.f) ? e.w : 0.2f * e.w;
    items[nit++] = e;
    m.x = fmaxf(m.x, e.x); m.y = fmaxf(m.y, e.y);
    m.z = fmaxf(m.z, e.z); m.w = fmaxf(m.w, e.w);
  }
#pragma unroll
  for (int d = 1; d < 64; d <<= 1) {
    m.x = fmaxf(m.x, __shfl_xor(m.x, d));
    m.y = fmaxf(m.y, __shfl_xor(m.y, d));
    m.z = fmaxf(m.z, __shfl_xor(m.z, d));
    m.w = fmaxf(m.w, __shfl_xor(m.w, d));
  }
  float4 s = make_float4(0.f, 0.f, 0.f, 0.f);
  for (int i = 0; i < nit; i++) {
    s.x += __expf(items[i].x - m.x);
    s.y += __expf(items[i].y - m.y);
    s.z += __expf(items[i].z - m.z);
    s.w += __expf(items[i].w - m.w);
  }
#pragma unroll
  for (int d = 1; d < 64; d <<= 1) {
    s.x += __shfl_xor(s.x, d);
    s.y += __shfl_xor(s.y, d);
    s.z += __shfl_xor(s.z, d);
    s.w += __shfl_xor(s.w, d);
  }
  if (lane == 0) {
    *(float4*)&m_arr[node * 4] = m;
    float4 li;
    li.x = 1.f / (s.x + 1e-16f);
    li.y = 1.f / (s.y + 1e-16f);
    li.z = 1.f / (s.z + 1e-16f);
    li.w = 1.f / (s.w + 1e-16f);
    *(float4*)&linv_arr[node * 4] = li;
  }
}

// ---------------- aggregation: plain weighted sum, 2 indep chains ----------------
__global__ __launch_bounds__(256) void k_agg(
    const float* __restrict__ h, const float* __restrict__ a_src,
    const float* __restrict__ a_dst, const int* __restrict__ cnt,
    const unsigned short* __restrict__ nbr, const float* __restrict__ m_arr,
    const float* __restrict__ linv_arr, const float* __restrict__ bias,
    float* __restrict__ feat) {
  const int lane = threadIdx.x & 63;
  int nb = (blockIdx.x & 7) * (N_NODES / 4 / 8) + (blockIdx.x >> 3);
  const int node = nb * 4 + (threadIdx.x >> 6);
  const int head = lane >> 4;
  const int c0 = lane * 4;
  const int base = node & ~(NPG - 1);
  const float ad = a_dst[node * 4 + head];
  const float m = m_arr[node * 4 + head];
  const float linv = linv_arr[node * 4 + head];
  int n = cnt[node];
  if (n > CAP) n = CAP;
  float4 acc0 = make_float4(0.f, 0.f, 0.f, 0.f);
  float4 acc1 = make_float4(0.f, 0.f, 0.f, 0.f);
  int j = 0;
  for (; j + 1 < n; j += 2) {
    int s0 = base + (int)nbr[(size_t)node * CAP + j];
    int s1 = base + (int)nbr[(size_t)node * CAP + j + 1];
    float e0 = a_src[s0 * 4 + head] + ad;
    float e1 = a_src[s1 * 4 + head] + ad;
    e0 = (e0 > 0.f) ? e0 : 0.2f * e0;
    e1 = (e1 > 0.f) ? e1 : 0.2f * e1;
    float p0 = __expf(e0 - m) * linv;
    float p1 = __expf(e1 - m) * linv;
    float4 h0 = *(const float4*)&h[(size_t)s0 * 256 + c0];
    float4 h1 = *(const float4*)&h[(size_t)s1 * 256 + c0];
    acc0.x = fmaf(p0, h0.x, acc0.x); acc1.x = fmaf(p1, h1.x, acc1.x);
    acc0.y = fmaf(p0, h0.y, acc0.y); acc1.y = fmaf(p1, h1.y, acc1.y);
    acc0.z = fmaf(p0, h0.z, acc0.z); acc1.z = fmaf(p1, h1.z, acc1.z);
    acc0.w = fmaf(p0, h0.w, acc0.w); acc1.w = fmaf(p1, h1.w, acc1.w);
  }
  if (j < n) {
    int s0 = base + (int)nbr[(size_t)node * CAP + j];
    float e0 = a_src[s0 * 4 + head] + ad;
    e0 = (e0 > 0.f) ? e0 : 0.2f * e0;
    float p0 = __expf(e0 - m) * linv;
    float4 h0 = *(const float4*)&h[(size_t)s0 * 256 + c0];
    acc0.x = fmaf(p0, h0.x, acc0.x);
    acc0.y = fmaf(p0, h0.y, acc0.y);
    acc0.z = fmaf(p0, h0.z, acc0.z);
    acc0.w = fmaf(p0, h0.w, acc0.w);
  }
  {  // self loop
    float e0 = a_src[node * 4 + head] + ad;
    e0 = (e0 > 0.f) ? e0 : 0.2f * e0;
    float p0 = __expf(e0 - m) * linv;
    float4 h0 = *(const float4*)&h[(size_t)node * 256 + c0];
    acc1.x = fmaf(p0, h0.x, acc1.x);
    acc1.y = fmaf(p0, h0.y, acc1.y);
    acc1.z = fmaf(p0, h0.z, acc1.z);
    acc1.w = fmaf(p0, h0.w, acc1.w);
  }
  const float4 b4 = *(const float4*)&bias[c0];
  float4 o;
  o.x = fmaxf(acc0.x + acc1.x + b4.x, 0.f);
  o.y = fmaxf(acc0.y + acc1.y + b4.y, 0.f);
  o.z = fmaxf(acc0.z + acc1.z + b4.z, 0.f);
  o.w = fmaxf(acc0.w + acc1.w + b4.w, 0.f);
  *(float4*)&feat[(size_t)node * 256 + c0] = o;
}

// ---------------- BN stats ----------------
__global__ __launch_bounds__(256) void k_bn_partial(const float* __restrict__ feat,
                                                    double* __restrict__ psum,
                                                    double* __restrict__ psq) {
  const int c = threadIdx.x;
  const int r0 = blockIdx.x * 128;
  double s = 0.0, q = 0.0;
  for (int i = 0; i < 128; i++) {
    double v = (double)feat[(size_t)(r0 + i) * 256 + c];
    s += v;
    q += v * v;
  }
  psum[blockIdx.x * 256 + c] = s;
  psq[blockIdx.x * 256 + c] = q;
}

__global__ __launch_bounds__(256) void k_bn_final(
    const double* __restrict__ psum, const double* __restrict__ psq,
    const float* __restrict__ gam, const float* __restrict__ bet,
    const float* __restrict__ pw, float* __restrict__ cA, float* __restrict__ cB,
    float* __restrict__ pwn) {
  __shared__ double wsq[256];
  const int c = threadIdx.x;
  double s = 0.0, q = 0.0;
  for (int i = 0; i < 256; i++) {
    s += psum[i * 256 + c];
    q += psq[i * 256 + c];
  }
  double mean = s / (double)N_NODES;
  double var = q / (double)N_NODES - mean * mean;
  double a = (double)gam[c] / sqrt(var + 1e-5);
  cA[c] = (float)a;
  cB[c] = (float)((double)bet[c] - mean * a);
  double w = (double)pw[c];
  wsq[c] = w * w;
  __syncthreads();
  if (c == 0) {
    double nn = 0.0;
    for (int i = 0; i < 256; i++) nn += wsq[i];
    wsq[0] = sqrt(nn);
  }
  __syncthreads();
  pwn[c] = (float)((double)pw[c] / wsq[0]);
}

// ---------------- score ----------------
__global__ __launch_bounds__(256) void k_score(
    const float* __restrict__ feat, const float* __restrict__ cA,
    const float* __restrict__ cB, const float* __restrict__ pwn,
    float* __restrict__ score) {
  const int lane = threadIdx.x & 63;
  const int node = blockIdx.x * 4 + (threadIdx.x >> 6);
  const int c0 = lane * 4;
  float4 f = *(const float4*)&feat[(size_t)node * 256 + c0];
  float4 a = *(const float4*)&cA[c0];
  float4 b = *(const float4*)&cB[c0];
  float4 w = *(const float4*)&pwn[c0];
  float p = fmaf(f.x, a.x, b.x) * w.x + fmaf(f.y, a.y, b.y) * w.y +
            fmaf(f.z, a.z, b.z) * w.z + fmaf(f.w, a.w, b.w) * w.w;
#pragma unroll
  for (int d = 1; d < 64; d <<= 1) p += __shfl_xor(p, d, 64);
  if (lane == 0) score[node] = p;
}

// ---------------- topk + gather ----------------
__global__ __launch_bounds__(512) void k_topk(
    const float* __restrict__ score, const float* __restrict__ feat,
    const float* __restrict__ cA, const float* __restrict__ cB,
    float* __restrict__ out) {
  __shared__ float ss[NPG];
  __shared__ int sel[KKEEP];
  __shared__ float gate[KKEEP];
  const int g = blockIdx.x;
  const int t = threadIdx.x;
  float s = score[g * NPG + t];
  ss[t] = s;
  __syncthreads();
  int rank = 0;
  for (int j = 0; j < NPG; j++) {
    float sj = ss[j];
    rank += (sj > s || (sj == s && j < t)) ? 1 : 0;
  }
  if (rank < KKEEP) {
    sel[rank] = t;
    gate[rank] = tanhf(s);
  }
  __syncthreads();
  for (int idx = t; idx < KKEEP * 64; idx += 512) {
    int r = idx >> 6;
    int c4 = (idx & 63) * 4;
    int node = g * NPG + sel[r];
    float4 f = *(const float4*)&feat[(size_t)node * 256 + c4];
    float4 a = *(const float4*)&cA[c4];
    float4 b = *(const float4*)&cB[c4];
    float tg = gate[r];
    float4 o;
    o.x = fmaf(f.x, a.x, b.x) * tg;
    o.y = fmaf(f.y, a.y, b.y) * tg;
    o.z = fmaf(f.z, a.z, b.z) * tg;
    o.w = fmaf(f.w, a.w, b.w) * tg;
    *(float4*)&out[(size_t)(g * KKEEP + r) * 256 + c4] = o;
  }
}

extern "C" void kernel_launch(void* const* d_in, const int* in_sizes, int n_in,
                              void* d_out, int out_size, void* d_ws, size_t ws_size,
                              hipStream_t stream) {
  const float* x    = (const float*)d_in[0];
  const int*   ei   = (const int*)d_in[1];
  const float* W    = (const float*)d_in[2];
  const float* attS = (const float*)d_in[3];
  const float* attD = (const float*)d_in[4];
  const float* bias = (const float*)d_in[5];
  const float* gam  = (const float*)d_in[6];
  const float* bet  = (const float*)d_in[7];
  const float* pw   = (const float*)d_in[8];
  float* out = (float*)d_out;
  const int E = in_sizes[1] / 2;

  char* p = (char*)d_ws;
  float* h     = (float*)p; p += (size_t)N_NODES * 256 * 4;
  float* feat  = (float*)p; p += (size_t)N_NODES * 256 * 4;
  float* a_src = (float*)p; p += (size_t)N_NODES * 4 * 4;
  float* a_dst = (float*)p; p += (size_t)N_NODES * 4 * 4;
  float* m_arr = (float*)p; p += (size_t)N_NODES * 4 * 4;
  float* linv  = (float*)p; p += (size_t)N_NODES * 4 * 4;
  float* score = (float*)p; p += (size_t)N_NODES * 4;
  double* psum = (double*)p; p += (size_t)256 * 256 * 8;
  double* psq  = (double*)p; p += (size_t)256 * 256 * 8;
  float* cA    = (float*)p; p += 256 * 4;
  float* cB    = (float*)p; p += 256 * 4;
  float* pwn   = (float*)p; p += 256 * 4;
  int* cnt     = (int*)p;   p += (size_t)N_NODES * 4;
  unsigned short* nbr = (unsigned short*)p; p += (size_t)N_NODES * CAP * 2;

  hipMemsetAsync(cnt, 0, (size_t)N_NODES * 4, stream);
  k_hist<<<(E + 255) / 256, 256, 0, stream>>>(ei, E, cnt, nbr);
  k_gemm<<<N_NODES / 64, 256, 0, stream>>>(x, W, attS, attD, h, a_src, a_dst);
  k_soft<<<N_NODES / 4, 256, 0, stream>>>(a_src, a_dst, cnt, nbr, m_arr, linv);
  k_agg<<<N_NODES / 4, 256, 0, stream>>>(h, a_src, a_dst, cnt, nbr, m_arr, linv, bias, feat);
  k_bn_partial<<<256, 256, 0, stream>>>(feat, psum, psq);
  k_bn_final<<<1, 256, 0, stream>>>(psum, psq, gam, bet, pw, cA, cB, pwn);
  k_score<<<N_NODES / 4, 256, 0, stream>>>(feat, cA, cB, pwn, score);
  k_topk<<<NGRAPH, 512, 0, stream>>>(score, feat, cA, cB, out);
}

// Round 4
// 298.586 us; speedup vs baseline: 1.0241x; 1.0241x over previous
//
#include <hip/hip_runtime.h>
#include <math.h>

#define N_NODES 32768
#define NPG 512
#define NGRAPH 64
#define KKEEP 256
#define CAP 64

typedef __attribute__((ext_vector_type(8))) short short8;
typedef __attribute__((ext_vector_type(4))) float f32x4;
typedef unsigned short ushort_t;

__device__ __forceinline__ unsigned short f2bf(float v) {
  unsigned u = __builtin_bit_cast(unsigned, v);
  u = (u + 0x7FFFu + ((u >> 16) & 1u)) >> 16;
  return (unsigned short)u;
}
__device__ __forceinline__ float bf2f(unsigned short u) {
  unsigned v = ((unsigned)u) << 16;
  return __builtin_bit_cast(float, v);
}

// ---- convert x -> (hi,lo) bf16; W -> transposed (hi,lo,lolo) bf16 ----
__global__ __launch_bounds__(256) void k_conv(
    const float* __restrict__ x, const float* __restrict__ W,
    unsigned short* __restrict__ xh, unsigned short* __restrict__ xl,
    unsigned short* __restrict__ wth, unsigned short* __restrict__ wtl,
    unsigned short* __restrict__ wtll) {
  const int t = threadIdx.x;
  if (blockIdx.x < 2048) {
    size_t base = ((size_t)blockIdx.x * 256 + t) * 16;
    unsigned short hb[16], lb[16];
#pragma unroll
    for (int g = 0; g < 4; g++) {
      float4 v = *(const float4*)&x[base + g * 4];
      float f[4] = {v.x, v.y, v.z, v.w};
#pragma unroll
      for (int j = 0; j < 4; j++) {
        unsigned short hh = f2bf(f[j]);
        float e1 = f[j] - bf2f(hh);          // exact
        hb[g * 4 + j] = hh;
        lb[g * 4 + j] = f2bf(e1);
      }
    }
    *(uint4*)&xh[base] = *(uint4*)&hb[0];
    *(uint4*)&xh[base + 8] = *(uint4*)&hb[8];
    *(uint4*)&xl[base] = *(uint4*)&lb[0];
    *(uint4*)&xl[base + 8] = *(uint4*)&lb[8];
  } else {
    int bw = blockIdx.x - 2048;              // 0..63
    int n = bw * 4 + (t >> 6);               // output col of W
    int k = (t & 63) * 4;
    unsigned short hb[4], lb[4], qb[4];
#pragma unroll
    for (int j = 0; j < 4; j++) {
      float v = W[(size_t)(k + j) * 256 + n];
      unsigned short hh = f2bf(v);
      float e1 = v - bf2f(hh);               // exact
      unsigned short ll = f2bf(e1);
      float e2 = e1 - bf2f(ll);              // exact
      hb[j] = hh; lb[j] = ll; qb[j] = f2bf(e2);
    }
    *(uint2*)&wth[(size_t)n * 256 + k] = *(uint2*)&hb[0];
    *(uint2*)&wtl[(size_t)n * 256 + k] = *(uint2*)&lb[0];
    *(uint2*)&wtll[(size_t)n * 256 + k] = *(uint2*)&qb[0];
  }
}

// ---- MFMA split-3 bf16 GEMM: h = x@W (+fused a_src/a_dst) ----
// grid: 256 m-blocks x 2 n-halves; tile 128x128, 4 waves of 64x64
__global__ __launch_bounds__(256) void k_gemm(
    const float* __restrict__ x,
    const unsigned short* __restrict__ xhp, const unsigned short* __restrict__ xlp,
    const unsigned short* __restrict__ wth, const unsigned short* __restrict__ wtl,
    const unsigned short* __restrict__ wtll,
    const float* __restrict__ attS, const float* __restrict__ attD,
    float* __restrict__ h, float* __restrict__ a_src, float* __restrict__ a_dst) {
  __shared__ unsigned short As[3][128][40];  // [hi/lo/lolo][m][k], pad 32->40
  __shared__ unsigned short Bs[3][128][40];  // [hi/lo/lolo][n][k]
  const int t = threadIdx.x;
  const int mb = blockIdx.x >> 1, nh = blockIdx.x & 1;
  const int row0 = mb * 128;
  const int wid = t >> 6, lane = t & 63;
  const int q = lane >> 4, ln = lane & 15;
  const int wm = (wid >> 1) * 64, wn = (wid & 1) * 64;
  f32x4 acc[4][4] = {};

  for (int kc = 0; kc < 8; kc++) {
    const int k0 = kc * 32;
#pragma unroll
    for (int i = 0; i < 2; i++) {
      int c = i * 256 + t;
      int r = c >> 2, ko = (c & 3) * 8;
      size_t ga = (size_t)(row0 + r) * 256 + k0 + ko;
      uint4 vh = *(const uint4*)&xhp[ga];
      uint4 vl = *(const uint4*)&xlp[ga];
      *(uint4*)&As[0][r][ko] = vh;
      *(uint4*)&As[1][r][ko] = vl;
      float4 f0 = *(const float4*)&x[ga];
      float4 f1 = *(const float4*)&x[ga + 4];
      unsigned short hs[8], ls[8], qs[8];
      *(uint4*)&hs[0] = vh;
      *(uint4*)&ls[0] = vl;
      float ff[8] = {f0.x, f0.y, f0.z, f0.w, f1.x, f1.y, f1.z, f1.w};
#pragma unroll
      for (int j = 0; j < 8; j++)
        qs[j] = f2bf(ff[j] - bf2f(hs[j]) - bf2f(ls[j]));   // exact residual
      *(uint4*)&As[2][r][ko] = *(uint4*)&qs[0];
      size_t gb = (size_t)(nh * 128 + r) * 256 + k0 + ko;
      *(uint4*)&Bs[0][r][ko] = *(const uint4*)&wth[gb];
      *(uint4*)&Bs[1][r][ko] = *(const uint4*)&wtl[gb];
      *(uint4*)&Bs[2][r][ko] = *(const uint4*)&wtll[gb];
    }
    __syncthreads();
    short8 ah[4], al[4], aq[4];
#pragma unroll
    for (int mt = 0; mt < 4; mt++) {
      ah[mt] = *(const short8*)&As[0][wm + mt * 16 + ln][q * 8];
      al[mt] = *(const short8*)&As[1][wm + mt * 16 + ln][q * 8];
      aq[mt] = *(const short8*)&As[2][wm + mt * 16 + ln][q * 8];
    }
#pragma unroll
    for (int nt = 0; nt < 4; nt++) {
      short8 bh = *(const short8*)&Bs[0][wn + nt * 16 + ln][q * 8];
      short8 bl = *(const short8*)&Bs[1][wn + nt * 16 + ln][q * 8];
      short8 bq = *(const short8*)&Bs[2][wn + nt * 16 + ln][q * 8];
#pragma unroll
      for (int mt = 0; mt < 4; mt++) {
        acc[mt][nt] = __builtin_amdgcn_mfma_f32_16x16x32_bf16(ah[mt], bh, acc[mt][nt], 0, 0, 0);
        acc[mt][nt] = __builtin_amdgcn_mfma_f32_16x16x32_bf16(ah[mt], bl, acc[mt][nt], 0, 0, 0);
        acc[mt][nt] = __builtin_amdgcn_mfma_f32_16x16x32_bf16(al[mt], bh, acc[mt][nt], 0, 0, 0);
        acc[mt][nt] = __builtin_amdgcn_mfma_f32_16x16x32_bf16(ah[mt], bq, acc[mt][nt], 0, 0, 0);
        acc[mt][nt] = __builtin_amdgcn_mfma_f32_16x16x32_bf16(al[mt], bl, acc[mt][nt], 0, 0, 0);
        acc[mt][nt] = __builtin_amdgcn_mfma_f32_16x16x32_bf16(aq[mt], bh, acc[mt][nt], 0, 0, 0);
      }
    }
    __syncthreads();
  }
  // epilogue: store h + per-head attention dots (wave covers one head)
  const int head = nh * 2 + (wid & 1);
  float sA[4], sD[4];
#pragma unroll
  for (int nt = 0; nt < 4; nt++) {
    int n = nh * 128 + wn + nt * 16 + ln;
    sA[nt] = attS[n];
    sD[nt] = attD[n];
  }
#pragma unroll
  for (int mt = 0; mt < 4; mt++) {
#pragma unroll
    for (int reg = 0; reg < 4; reg++) {
      int m = row0 + wm + mt * 16 + q * 4 + reg;
      float ps = 0.f, pd = 0.f;
#pragma unroll
      for (int nt = 0; nt < 4; nt++) {
        float v = acc[mt][nt][reg];
        h[(size_t)m * 256 + nh * 128 + wn + nt * 16 + ln] = v;
        ps = fmaf(v, sA[nt], ps);
        pd = fmaf(v, sD[nt], pd);
      }
#pragma unroll
      for (int d = 1; d < 16; d <<= 1) {
        ps += __shfl_xor(ps, d, 16);
        pd += __shfl_xor(pd, d, 16);
      }
      if (ln == 0) {
        a_src[m * 4 + head] = ps;
        a_dst[m * 4 + head] = pd;
      }
    }
  }
}

// ---- edge bucketing by dst (local ushort indices) ----
__global__ void k_hist(const int* __restrict__ ei, int E, int* __restrict__ cnt,
                       unsigned short* __restrict__ nbr) {
  int e = blockIdx.x * 256 + threadIdx.x;
  if (e < E) {
    int s = ei[e];
    int d = ei[E + e];
    int slot = atomicAdd(&cnt[d], 1);
    if (slot < CAP) nbr[(size_t)d * CAP + slot] = (unsigned short)(s & (NPG - 1));
  }
}

// ---- softmax stats per node ----
__global__ __launch_bounds__(256) void k_soft(
    const float* __restrict__ a_src, const float* __restrict__ a_dst,
    const int* __restrict__ cnt, const unsigned short* __restrict__ nbr,
    float* __restrict__ m_arr, float* __restrict__ linv_arr) {
  const int lane = threadIdx.x & 63;
  int nb = (blockIdx.x & 7) * (N_NODES / 4 / 8) + (blockIdx.x >> 3);
  const int node = nb * 4 + (threadIdx.x >> 6);
  const int base = node & ~(NPG - 1);
  int n = cnt[node];
  if (n > CAP) n = CAP;
  const float4 ad = *(const float4*)&a_dst[node * 4];
  float4 items[2];
  int nit = 0;
  float4 m = make_float4(-1e30f, -1e30f, -1e30f, -1e30f);
  for (int j = lane; j <= n; j += 64) {
    int src = (j < n) ? base + (int)nbr[(size_t)node * CAP + j] : node;
    float4 as = *(const float4*)&a_src[src * 4];
    float4 e;
    e.x = as.x + ad.x; e.x = (e.x > 0.f) ? e.x : 0.2f * e.x;
    e.y = as.y + ad.y; e.y = (e.y > 0.f) ? e.y : 0.2f * e.y;
    e.z = as.z + ad.z; e.z = (e.z > 0.f) ? e.z : 0.2f * e.z;
    e.w = as.w + ad.w; e.w = (e.w > 0.f) ? e.w : 0.2f * e.w;
    items[nit++] = e;
    m.x = fmaxf(m.x, e.x); m.y = fmaxf(m.y, e.y);
    m.z = fmaxf(m.z, e.z); m.w = fmaxf(m.w, e.w);
  }
#pragma unroll
  for (int d = 1; d < 64; d <<= 1) {
    m.x = fmaxf(m.x, __shfl_xor(m.x, d));
    m.y = fmaxf(m.y, __shfl_xor(m.y, d));
    m.z = fmaxf(m.z, __shfl_xor(m.z, d));
    m.w = fmaxf(m.w, __shfl_xor(m.w, d));
  }
  float4 s = make_float4(0.f, 0.f, 0.f, 0.f);
  for (int i = 0; i < nit; i++) {
    s.x += __expf(items[i].x - m.x);
    s.y += __expf(items[i].y - m.y);
    s.z += __expf(items[i].z - m.z);
    s.w += __expf(items[i].w - m.w);
  }
#pragma unroll
  for (int d = 1; d < 64; d <<= 1) {
    s.x += __shfl_xor(s.x, d);
    s.y += __shfl_xor(s.y, d);
    s.z += __shfl_xor(s.z, d);
    s.w += __shfl_xor(s.w, d);
  }
  if (lane == 0) {
    *(float4*)&m_arr[node * 4] = m;
    float4 li;
    li.x = 1.f / (s.x + 1e-16f);
    li.y = 1.f / (s.y + 1e-16f);
    li.z = 1.f / (s.z + 1e-16f);
    li.w = 1.f / (s.w + 1e-16f);
    *(float4*)&linv_arr[node * 4] = li;
  }
}

// ---- aggregation ----
__global__ __launch_bounds__(256) void k_agg(
    const float* __restrict__ h, const float* __restrict__ a_src,
    const float* __restrict__ a_dst, const int* __restrict__ cnt,
    const unsigned short* __restrict__ nbr, const float* __restrict__ m_arr,
    const float* __restrict__ linv_arr, const float* __restrict__ bias,
    float* __restrict__ feat) {
  const int lane = threadIdx.x & 63;
  int nb = (blockIdx.x & 7) * (N_NODES / 4 / 8) + (blockIdx.x >> 3);
  const int node = nb * 4 + (threadIdx.x >> 6);
  const int head = lane >> 4;
  const int c0 = lane * 4;
  const int base = node & ~(NPG - 1);
  const float ad = a_dst[node * 4 + head];
  const float m = m_arr[node * 4 + head];
  const float linv = linv_arr[node * 4 + head];
  int n = cnt[node];
  if (n > CAP) n = CAP;
  float4 acc0 = make_float4(0.f, 0.f, 0.f, 0.f);
  float4 acc1 = make_float4(0.f, 0.f, 0.f, 0.f);
  int j = 0;
  for (; j + 1 < n; j += 2) {
    int s0 = base + (int)nbr[(size_t)node * CAP + j];
    int s1 = base + (int)nbr[(size_t)node * CAP + j + 1];
    float e0 = a_src[s0 * 4 + head] + ad;
    float e1 = a_src[s1 * 4 + head] + ad;
    e0 = (e0 > 0.f) ? e0 : 0.2f * e0;
    e1 = (e1 > 0.f) ? e1 : 0.2f * e1;
    float p0 = __expf(e0 - m) * linv;
    float p1 = __expf(e1 - m) * linv;
    float4 h0 = *(const float4*)&h[(size_t)s0 * 256 + c0];
    float4 h1 = *(const float4*)&h[(size_t)s1 * 256 + c0];
    acc0.x = fmaf(p0, h0.x, acc0.x); acc1.x = fmaf(p1, h1.x, acc1.x);
    acc0.y = fmaf(p0, h0.y, acc0.y); acc1.y = fmaf(p1, h1.y, acc1.y);
    acc0.z = fmaf(p0, h0.z, acc0.z); acc1.z = fmaf(p1, h1.z, acc1.z);
    acc0.w = fmaf(p0, h0.w, acc0.w); acc1.w = fmaf(p1, h1.w, acc1.w);
  }
  if (j < n) {
    int s0 = base + (int)nbr[(size_t)node * CAP + j];
    float e0 = a_src[s0 * 4 + head] + ad;
    e0 = (e0 > 0.f) ? e0 : 0.2f * e0;
    float p0 = __expf(e0 - m) * linv;
    float4 h0 = *(const float4*)&h[(size_t)s0 * 256 + c0];
    acc0.x = fmaf(p0, h0.x, acc0.x);
    acc0.y = fmaf(p0, h0.y, acc0.y);
    acc0.z = fmaf(p0, h0.z, acc0.z);
    acc0.w = fmaf(p0, h0.w, acc0.w);
  }
  {  // self loop
    float e0 = a_src[node * 4 + head] + ad;
    e0 = (e0 > 0.f) ? e0 : 0.2f * e0;
    float p0 = __expf(e0 - m) * linv;
    float4 h0 = *(const float4*)&h[(size_t)node * 256 + c0];
    acc1.x = fmaf(p0, h0.x, acc1.x);
    acc1.y = fmaf(p0, h0.y, acc1.y);
    acc1.z = fmaf(p0, h0.z, acc1.z);
    acc1.w = fmaf(p0, h0.w, acc1.w);
  }
  const float4 b4 = *(const float4*)&bias[c0];
  float4 o;
  o.x = fmaxf(acc0.x + acc1.x + b4.x, 0.f);
  o.y = fmaxf(acc0.y + acc1.y + b4.y, 0.f);
  o.z = fmaxf(acc0.z + acc1.z + b4.z, 0.f);
  o.w = fmaxf(acc0.w + acc1.w + b4.w, 0.f);
  *(float4*)&feat[(size_t)node * 256 + c0] = o;
}

// ---- BN stats ----
__global__ __launch_bounds__(256) void k_bn_partial(const float* __restrict__ feat,
                                                    double* __restrict__ psum,
                                                    double* __restrict__ psq) {
  const int c = threadIdx.x;
  const int r0 = blockIdx.x * 128;
  double s = 0.0, q = 0.0;
  for (int i = 0; i < 128; i++) {
    double v = (double)feat[(size_t)(r0 + i) * 256 + c];
    s += v;
    q += v * v;
  }
  psum[blockIdx.x * 256 + c] = s;
  psq[blockIdx.x * 256 + c] = q;
}

__global__ __launch_bounds__(256) void k_bn_final(
    const double* __restrict__ psum, const double* __restrict__ psq,
    const float* __restrict__ gam, const float* __restrict__ bet,
    const float* __restrict__ pw, float* __restrict__ cA, float* __restrict__ cB,
    float* __restrict__ pwn) {
  __shared__ double wsq[256];
  const int c = threadIdx.x;
  double s = 0.0, q = 0.0;
  for (int i = 0; i < 256; i++) {
    s += psum[i * 256 + c];
    q += psq[i * 256 + c];
  }
  double mean = s / (double)N_NODES;
  double var = q / (double)N_NODES - mean * mean;
  double a = (double)gam[c] / sqrt(var + 1e-5);
  cA[c] = (float)a;
  cB[c] = (float)((double)bet[c] - mean * a);
  double w = (double)pw[c];
  wsq[c] = w * w;
  __syncthreads();
  if (c == 0) {
    double nn = 0.0;
    for (int i = 0; i < 256; i++) nn += wsq[i];
    wsq[0] = sqrt(nn);
  }
  __syncthreads();
  pwn[c] = (float)((double)pw[c] / wsq[0]);
}

// ---- score ----
__global__ __launch_bounds__(256) void k_score(
    const float* __restrict__ feat, const float* __restrict__ cA,
    const float* __restrict__ cB, const float* __restrict__ pwn,
    float* __restrict__ score) {
  const int lane = threadIdx.x & 63;
  const int node = blockIdx.x * 4 + (threadIdx.x >> 6);
  const int c0 = lane * 4;
  float4 f = *(const float4*)&feat[(size_t)node * 256 + c0];
  float4 a = *(const float4*)&cA[c0];
  float4 b = *(const float4*)&cB[c0];
  float4 w = *(const float4*)&pwn[c0];
  float p = fmaf(f.x, a.x, b.x) * w.x + fmaf(f.y, a.y, b.y) * w.y +
            fmaf(f.z, a.z, b.z) * w.z + fmaf(f.w, a.w, b.w) * w.w;
#pragma unroll
  for (int d = 1; d < 64; d <<= 1) p += __shfl_xor(p, d, 64);
  if (lane == 0) score[node] = p;
}

// ---- topk + gather ----
__global__ __launch_bounds__(512) void k_topk(
    const float* __restrict__ score, const float* __restrict__ feat,
    const float* __restrict__ cA, const float* __restrict__ cB,
    float* __restrict__ out) {
  __shared__ float ss[NPG];
  __shared__ int sel[KKEEP];
  __shared__ float gate[KKEEP];
  const int g = blockIdx.x;
  const int t = threadIdx.x;
  float s = score[g * NPG + t];
  ss[t] = s;
  __syncthreads();
  int rank = 0;
  for (int j = 0; j < NPG; j++) {
    float sj = ss[j];
    rank += (sj > s || (sj == s && j < t)) ? 1 : 0;
  }
  if (rank < KKEEP) {
    sel[rank] = t;
    gate[rank] = tanhf(s);
  }
  __syncthreads();
  for (int idx = t; idx < KKEEP * 64; idx += 512) {
    int r = idx >> 6;
    int c4 = (idx & 63) * 4;
    int node = g * NPG + sel[r];
    float4 f = *(const float4*)&feat[(size_t)node * 256 + c4];
    float4 a = *(const float4*)&cA[c4];
    float4 b = *(const float4*)&cB[c4];
    float tg = gate[r];
    float4 o;
    o.x = fmaf(f.x, a.x, b.x) * tg;
    o.y = fmaf(f.y, a.y, b.y) * tg;
    o.z = fmaf(f.z, a.z, b.z) * tg;
    o.w = fmaf(f.w, a.w, b.w) * tg;
    *(float4*)&out[(size_t)(g * KKEEP + r) * 256 + c4] = o;
  }
}

extern "C" void kernel_launch(void* const* d_in, const int* in_sizes, int n_in,
                              void* d_out, int out_size, void* d_ws, size_t ws_size,
                              hipStream_t stream) {
  const float* x    = (const float*)d_in[0];
  const int*   ei   = (const int*)d_in[1];
  const float* W    = (const float*)d_in[2];
  const float* attS = (const float*)d_in[3];
  const float* attD = (const float*)d_in[4];
  const float* bias = (const float*)d_in[5];
  const float* gam  = (const float*)d_in[6];
  const float* bet  = (const float*)d_in[7];
  const float* pw   = (const float*)d_in[8];
  float* out = (float*)d_out;
  const int E = in_sizes[1] / 2;

  char* p = (char*)d_ws;
  float* h     = (float*)p; p += (size_t)N_NODES * 256 * 4;
  // region shared by (x_hi,x_lo) [dead after k_gemm] and feat [born in k_agg]
  char* region = p;         p += (size_t)N_NODES * 256 * 4;
  unsigned short* xh = (unsigned short*)region;
  unsigned short* xl = (unsigned short*)(region + (size_t)N_NODES * 256 * 2);
  float* feat  = (float*)region;
  float* a_src = (float*)p; p += (size_t)N_NODES * 4 * 4;
  float* a_dst = (float*)p; p += (size_t)N_NODES * 4 * 4;
  float* m_arr = (float*)p; p += (size_t)N_NODES * 4 * 4;
  float* linv  = (float*)p; p += (size_t)N_NODES * 4 * 4;
  float* score = (float*)p; p += (size_t)N_NODES * 4;
  double* psum = (double*)p; p += (size_t)256 * 256 * 8;
  double* psq  = (double*)p; p += (size_t)256 * 256 * 8;
  float* cA    = (float*)p; p += 256 * 4;
  float* cB    = (float*)p; p += 256 * 4;
  float* pwn   = (float*)p; p += 256 * 4;
  unsigned short* wth  = (unsigned short*)p; p += (size_t)256 * 256 * 2;
  unsigned short* wtl  = (unsigned short*)p; p += (size_t)256 * 256 * 2;
  unsigned short* wtll = (unsigned short*)p; p += (size_t)256 * 256 * 2;
  int* cnt     = (int*)p;   p += (size_t)N_NODES * 4;
  unsigned short* nbr = (unsigned short*)p; p += (size_t)N_NODES * CAP * 2;

  hipMemsetAsync(cnt, 0, (size_t)N_NODES * 4, stream);
  k_hist<<<(E + 255) / 256, 256, 0, stream>>>(ei, E, cnt, nbr);
  k_conv<<<2112, 256, 0, stream>>>(x, W, xh, xl, wth, wtl, wtll);
  k_gemm<<<512, 256, 0, stream>>>(x, xh, xl, wth, wtl, wtll, attS, attD, h, a_src, a_dst);
  k_soft<<<N_NODES / 4, 256, 0, stream>>>(a_src, a_dst, cnt, nbr, m_arr, linv);
  k_agg<<<N_NODES / 4, 256, 0, stream>>>(h, a_src, a_dst, cnt, nbr, m_arr, linv, bias, feat);
  k_bn_partial<<<256, 256, 0, stream>>>(feat, psum, psq);
  k_bn_final<<<1, 256, 0, stream>>>(psum, psq, gam, bet, pw, cA, cB, pwn);
  k_score<<<N_NODES / 4, 256, 0, stream>>>(feat, cA, cB, pwn, score);
  k_topk<<<NGRAPH, 512, 0, stream>>>(score, feat, cA, cB, out);
}

// Round 5
// 256.530 us; speedup vs baseline: 1.1921x; 1.1639x over previous
//
#include <hip/hip_runtime.h>
#include <math.h>

#define N_NODES 32768
#define NPG 512
#define NGRAPH 64
#define KKEEP 256
#define CAP 64

typedef __attribute__((ext_vector_type(8))) short short8;
typedef __attribute__((ext_vector_type(4))) float f32x4;

__device__ __forceinline__ unsigned short f2bf(float v) {
  unsigned u = __builtin_bit_cast(unsigned, v);
  u = (u + 0x7FFFu + ((u >> 16) & 1u)) >> 16;
  return (unsigned short)u;
}
__device__ __forceinline__ float bf2f(unsigned short u) {
  unsigned v = ((unsigned)u) << 16;
  return __builtin_bit_cast(float, v);
}

// ---- convert x -> (hi,lo) bf16; W -> transposed (hi,lo,lolo) bf16 ----
__global__ __launch_bounds__(256) void k_conv(
    const float* __restrict__ x, const float* __restrict__ W,
    unsigned short* __restrict__ xh, unsigned short* __restrict__ xl,
    unsigned short* __restrict__ wth, unsigned short* __restrict__ wtl,
    unsigned short* __restrict__ wtll) {
  const int t = threadIdx.x;
  if (blockIdx.x < 2048) {
    size_t base = ((size_t)blockIdx.x * 256 + t) * 16;
    unsigned short hb[16], lb[16];
#pragma unroll
    for (int g = 0; g < 4; g++) {
      float4 v = *(const float4*)&x[base + g * 4];
      float f[4] = {v.x, v.y, v.z, v.w};
#pragma unroll
      for (int j = 0; j < 4; j++) {
        unsigned short hh = f2bf(f[j]);
        float e1 = f[j] - bf2f(hh);          // exact
        hb[g * 4 + j] = hh;
        lb[g * 4 + j] = f2bf(e1);
      }
    }
    *(uint4*)&xh[base] = *(uint4*)&hb[0];
    *(uint4*)&xh[base + 8] = *(uint4*)&hb[8];
    *(uint4*)&xl[base] = *(uint4*)&lb[0];
    *(uint4*)&xl[base + 8] = *(uint4*)&lb[8];
  } else {
    int bw = blockIdx.x - 2048;              // 0..63
    int n = bw * 4 + (t >> 6);               // output col of W
    int k = (t & 63) * 4;
    unsigned short hb[4], lb[4], qb[4];
#pragma unroll
    for (int j = 0; j < 4; j++) {
      float v = W[(size_t)(k + j) * 256 + n];
      unsigned short hh = f2bf(v);
      float e1 = v - bf2f(hh);               // exact
      unsigned short ll = f2bf(e1);
      float e2 = e1 - bf2f(ll);              // exact
      hb[j] = hh; lb[j] = ll; qb[j] = f2bf(e2);
    }
    *(uint2*)&wth[(size_t)n * 256 + k] = *(uint2*)&hb[0];
    *(uint2*)&wtl[(size_t)n * 256 + k] = *(uint2*)&lb[0];
    *(uint2*)&wtll[(size_t)n * 256 + k] = *(uint2*)&qb[0];
  }
}

// ---- MFMA split-3 bf16 GEMM: h = x@W (+fused a_src/a_dst) ----
__global__ __launch_bounds__(256) void k_gemm(
    const float* __restrict__ x,
    const unsigned short* __restrict__ xhp, const unsigned short* __restrict__ xlp,
    const unsigned short* __restrict__ wth, const unsigned short* __restrict__ wtl,
    const unsigned short* __restrict__ wtll,
    const float* __restrict__ attS, const float* __restrict__ attD,
    float* __restrict__ h, float* __restrict__ a_src, float* __restrict__ a_dst) {
  __shared__ unsigned short As[3][128][40];
  __shared__ unsigned short Bs[3][128][40];
  const int t = threadIdx.x;
  const int mb = blockIdx.x >> 1, nh = blockIdx.x & 1;
  const int row0 = mb * 128;
  const int wid = t >> 6, lane = t & 63;
  const int q = lane >> 4, ln = lane & 15;
  const int wm = (wid >> 1) * 64, wn = (wid & 1) * 64;
  f32x4 acc[4][4] = {};

  for (int kc = 0; kc < 8; kc++) {
    const int k0 = kc * 32;
#pragma unroll
    for (int i = 0; i < 2; i++) {
      int c = i * 256 + t;
      int r = c >> 2, ko = (c & 3) * 8;
      size_t ga = (size_t)(row0 + r) * 256 + k0 + ko;
      uint4 vh = *(const uint4*)&xhp[ga];
      uint4 vl = *(const uint4*)&xlp[ga];
      *(uint4*)&As[0][r][ko] = vh;
      *(uint4*)&As[1][r][ko] = vl;
      float4 f0 = *(const float4*)&x[ga];
      float4 f1 = *(const float4*)&x[ga + 4];
      unsigned short hs[8], ls[8], qs[8];
      *(uint4*)&hs[0] = vh;
      *(uint4*)&ls[0] = vl;
      float ff[8] = {f0.x, f0.y, f0.z, f0.w, f1.x, f1.y, f1.z, f1.w};
#pragma unroll
      for (int j = 0; j < 8; j++)
        qs[j] = f2bf(ff[j] - bf2f(hs[j]) - bf2f(ls[j]));   // exact residual
      *(uint4*)&As[2][r][ko] = *(uint4*)&qs[0];
      size_t gb = (size_t)(nh * 128 + r) * 256 + k0 + ko;
      *(uint4*)&Bs[0][r][ko] = *(const uint4*)&wth[gb];
      *(uint4*)&Bs[1][r][ko] = *(const uint4*)&wtl[gb];
      *(uint4*)&Bs[2][r][ko] = *(const uint4*)&wtll[gb];
    }
    __syncthreads();
    short8 ah[4], al[4], aq[4];
#pragma unroll
    for (int mt = 0; mt < 4; mt++) {
      ah[mt] = *(const short8*)&As[0][wm + mt * 16 + ln][q * 8];
      al[mt] = *(const short8*)&As[1][wm + mt * 16 + ln][q * 8];
      aq[mt] = *(const short8*)&As[2][wm + mt * 16 + ln][q * 8];
    }
#pragma unroll
    for (int nt = 0; nt < 4; nt++) {
      short8 bh = *(const short8*)&Bs[0][wn + nt * 16 + ln][q * 8];
      short8 bl = *(const short8*)&Bs[1][wn + nt * 16 + ln][q * 8];
      short8 bq = *(const short8*)&Bs[2][wn + nt * 16 + ln][q * 8];
#pragma unroll
      for (int mt = 0; mt < 4; mt++) {
        acc[mt][nt] = __builtin_amdgcn_mfma_f32_16x16x32_bf16(ah[mt], bh, acc[mt][nt], 0, 0, 0);
        acc[mt][nt] = __builtin_amdgcn_mfma_f32_16x16x32_bf16(ah[mt], bl, acc[mt][nt], 0, 0, 0);
        acc[mt][nt] = __builtin_amdgcn_mfma_f32_16x16x32_bf16(al[mt], bh, acc[mt][nt], 0, 0, 0);
        acc[mt][nt] = __builtin_amdgcn_mfma_f32_16x16x32_bf16(ah[mt], bq, acc[mt][nt], 0, 0, 0);
        acc[mt][nt] = __builtin_amdgcn_mfma_f32_16x16x32_bf16(al[mt], bl, acc[mt][nt], 0, 0, 0);
        acc[mt][nt] = __builtin_amdgcn_mfma_f32_16x16x32_bf16(aq[mt], bh, acc[mt][nt], 0, 0, 0);
      }
    }
    __syncthreads();
  }
  const int head = nh * 2 + (wid & 1);
  float sA[4], sD[4];
#pragma unroll
  for (int nt = 0; nt < 4; nt++) {
    int n = nh * 128 + wn + nt * 16 + ln;
    sA[nt] = attS[n];
    sD[nt] = attD[n];
  }
#pragma unroll
  for (int mt = 0; mt < 4; mt++) {
#pragma unroll
    for (int reg = 0; reg < 4; reg++) {
      int m = row0 + wm + mt * 16 + q * 4 + reg;
      float ps = 0.f, pd = 0.f;
#pragma unroll
      for (int nt = 0; nt < 4; nt++) {
        float v = acc[mt][nt][reg];
        h[(size_t)m * 256 + nh * 128 + wn + nt * 16 + ln] = v;
        ps = fmaf(v, sA[nt], ps);
        pd = fmaf(v, sD[nt], pd);
      }
#pragma unroll
      for (int d = 1; d < 16; d <<= 1) {
        ps += __shfl_xor(ps, d, 16);
        pd += __shfl_xor(pd, d, 16);
      }
      if (ln == 0) {
        a_src[m * 4 + head] = ps;
        a_dst[m * 4 + head] = pd;
      }
    }
  }
}

// ---- edge bucketing by dst (local ushort indices) ----
__global__ void k_hist(const int* __restrict__ ei, int E, int* __restrict__ cnt,
                       unsigned short* __restrict__ nbr) {
  int e = blockIdx.x * 256 + threadIdx.x;
  if (e < E) {
    int s = ei[e];
    int d = ei[E + e];
    int slot = atomicAdd(&cnt[d], 1);
    if (slot < CAP) nbr[(size_t)d * CAP + slot] = (unsigned short)(s & (NPG - 1));
  }
}

// ---- aggregation with fused softmax (max pass + weighted-sum pass) ----
__global__ __launch_bounds__(256) void k_agg(
    const float* __restrict__ h, const float* __restrict__ a_src,
    const float* __restrict__ a_dst, const int* __restrict__ cnt,
    const unsigned short* __restrict__ nbr, const float* __restrict__ bias,
    float* __restrict__ feat) {
  const int lane = threadIdx.x & 63;
  int nb = (blockIdx.x & 7) * (N_NODES / 4 / 8) + (blockIdx.x >> 3);
  const int node = nb * 4 + (threadIdx.x >> 6);
  const int head = lane >> 4;
  const int li = lane & 15;
  const int c0 = lane * 4;
  const int base = node & ~(NPG - 1);
  const float ad = a_dst[node * 4 + head];
  int n = cnt[node];
  if (n > CAP) n = CAP;
  // pass 1: per-head max over edges, lanes in head-group split the edges
  float m = -1e30f;
  for (int j = li; j < n; j += 16) {
    int s = base + (int)nbr[(size_t)node * CAP + j];
    float e = a_src[s * 4 + head] + ad;
    e = (e > 0.f) ? e : 0.2f * e;
    m = fmaxf(m, e);
  }
#pragma unroll
  for (int d = 1; d < 16; d <<= 1) m = fmaxf(m, __shfl_xor(m, d, 16));
  float es = a_src[node * 4 + head] + ad;   // self loop
  es = (es > 0.f) ? es : 0.2f * es;
  m = fmaxf(m, es);
  // pass 2: weighted sum + denominator (denominator redundant per lane-group)
  float4 acc0 = make_float4(0.f, 0.f, 0.f, 0.f);
  float4 acc1 = make_float4(0.f, 0.f, 0.f, 0.f);
  float l0 = 0.f, l1 = 0.f;
  int j = 0;
  for (; j + 1 < n; j += 2) {
    int s0 = base + (int)nbr[(size_t)node * CAP + j];
    int s1 = base + (int)nbr[(size_t)node * CAP + j + 1];
    float e0 = a_src[s0 * 4 + head] + ad;
    float e1 = a_src[s1 * 4 + head] + ad;
    e0 = (e0 > 0.f) ? e0 : 0.2f * e0;
    e1 = (e1 > 0.f) ? e1 : 0.2f * e1;
    float p0 = __expf(e0 - m);
    float p1 = __expf(e1 - m);
    l0 += p0; l1 += p1;
    float4 h0 = *(const float4*)&h[(size_t)s0 * 256 + c0];
    float4 h1 = *(const float4*)&h[(size_t)s1 * 256 + c0];
    acc0.x = fmaf(p0, h0.x, acc0.x); acc1.x = fmaf(p1, h1.x, acc1.x);
    acc0.y = fmaf(p0, h0.y, acc0.y); acc1.y = fmaf(p1, h1.y, acc1.y);
    acc0.z = fmaf(p0, h0.z, acc0.z); acc1.z = fmaf(p1, h1.z, acc1.z);
    acc0.w = fmaf(p0, h0.w, acc0.w); acc1.w = fmaf(p1, h1.w, acc1.w);
  }
  if (j < n) {
    int s0 = base + (int)nbr[(size_t)node * CAP + j];
    float e0 = a_src[s0 * 4 + head] + ad;
    e0 = (e0 > 0.f) ? e0 : 0.2f * e0;
    float p0 = __expf(e0 - m);
    l0 += p0;
    float4 h0 = *(const float4*)&h[(size_t)s0 * 256 + c0];
    acc0.x = fmaf(p0, h0.x, acc0.x);
    acc0.y = fmaf(p0, h0.y, acc0.y);
    acc0.z = fmaf(p0, h0.z, acc0.z);
    acc0.w = fmaf(p0, h0.w, acc0.w);
  }
  {  // self loop
    float p0 = __expf(es - m);
    l1 += p0;
    float4 h0 = *(const float4*)&h[(size_t)node * 256 + c0];
    acc1.x = fmaf(p0, h0.x, acc1.x);
    acc1.y = fmaf(p0, h0.y, acc1.y);
    acc1.z = fmaf(p0, h0.z, acc1.z);
    acc1.w = fmaf(p0, h0.w, acc1.w);
  }
  const float linv = 1.f / (l0 + l1 + 1e-16f);
  const float4 b4 = *(const float4*)&bias[c0];
  float4 o;
  o.x = fmaxf(fmaf(acc0.x + acc1.x, linv, b4.x), 0.f);
  o.y = fmaxf(fmaf(acc0.y + acc1.y, linv, b4.y), 0.f);
  o.z = fmaxf(fmaf(acc0.z + acc1.z, linv, b4.z), 0.f);
  o.w = fmaxf(fmaf(acc0.w + acc1.w, linv, b4.w), 0.f);
  *(float4*)&feat[(size_t)node * 256 + c0] = o;
}

// ---- BN stats ----
__global__ __launch_bounds__(256) void k_bn_partial(const float* __restrict__ feat,
                                                    double* __restrict__ psum,
                                                    double* __restrict__ psq) {
  const int c = threadIdx.x;
  const int r0 = blockIdx.x * 128;
  double s = 0.0, q = 0.0;
  for (int i = 0; i < 128; i++) {
    double v = (double)feat[(size_t)(r0 + i) * 256 + c];
    s += v;
    q += v * v;
  }
  psum[blockIdx.x * 256 + c] = s;
  psq[blockIdx.x * 256 + c] = q;
}

__global__ __launch_bounds__(1024) void k_bn_final(
    const double* __restrict__ psum, const double* __restrict__ psq,
    const float* __restrict__ gam, const float* __restrict__ bet,
    const float* __restrict__ pw, float* __restrict__ cA, float* __restrict__ cB,
    float* __restrict__ pwn) {
  __shared__ double reds[4][256];
  __shared__ double redq[4][256];
  __shared__ double wsq[256];
  const int t = threadIdx.x;
  const int c = t & 255, sl = t >> 8;
  double s = 0.0, q = 0.0;
  for (int i = sl * 64; i < sl * 64 + 64; i++) {
    s += psum[i * 256 + c];
    q += psq[i * 256 + c];
  }
  reds[sl][c] = s;
  redq[sl][c] = q;
  if (sl == 0) {
    double w = (double)pw[c];
    wsq[c] = w * w;
  }
  __syncthreads();
  if (t == 0) {
    double nn = 0.0;
    for (int i = 0; i < 256; i++) nn += wsq[i];
    wsq[0] = sqrt(nn);
  }
  if (sl == 0) {
    s = reds[0][c] + reds[1][c] + reds[2][c] + reds[3][c];
    q = redq[0][c] + redq[1][c] + redq[2][c] + redq[3][c];
    double mean = s / (double)N_NODES;
    double var = q / (double)N_NODES - mean * mean;
    double a = (double)gam[c] / sqrt(var + 1e-5);
    cA[c] = (float)a;
    cB[c] = (float)((double)bet[c] - mean * a);
  }
  __syncthreads();
  if (sl == 0) pwn[c] = (float)((double)pw[c] / wsq[0]);
}

// ---- score ----
__global__ __launch_bounds__(256) void k_score(
    const float* __restrict__ feat, const float* __restrict__ cA,
    const float* __restrict__ cB, const float* __restrict__ pwn,
    float* __restrict__ score) {
  const int lane = threadIdx.x & 63;
  const int node = blockIdx.x * 4 + (threadIdx.x >> 6);
  const int c0 = lane * 4;
  float4 f = *(const float4*)&feat[(size_t)node * 256 + c0];
  float4 a = *(const float4*)&cA[c0];
  float4 b = *(const float4*)&cB[c0];
  float4 w = *(const float4*)&pwn[c0];
  float p = fmaf(f.x, a.x, b.x) * w.x + fmaf(f.y, a.y, b.y) * w.y +
            fmaf(f.z, a.z, b.z) * w.z + fmaf(f.w, a.w, b.w) * w.w;
#pragma unroll
  for (int d = 1; d < 64; d <<= 1) p += __shfl_xor(p, d, 64);
  if (lane == 0) score[node] = p;
}

// ---- topk + gather ----
__global__ __launch_bounds__(512) void k_topk(
    const float* __restrict__ score, const float* __restrict__ feat,
    const float* __restrict__ cA, const float* __restrict__ cB,
    float* __restrict__ out) {
  __shared__ float ss[NPG];
  __shared__ int sel[KKEEP];
  __shared__ float gate[KKEEP];
  const int g = blockIdx.x;
  const int t = threadIdx.x;
  float s = score[g * NPG + t];
  ss[t] = s;
  __syncthreads();
  int rank = 0;
  for (int j = 0; j < NPG; j++) {
    float sj = ss[j];
    rank += (sj > s || (sj == s && j < t)) ? 1 : 0;
  }
  if (rank < KKEEP) {
    sel[rank] = t;
    gate[rank] = tanhf(s);
  }
  __syncthreads();
  for (int idx = t; idx < KKEEP * 64; idx += 512) {
    int r = idx >> 6;
    int c4 = (idx & 63) * 4;
    int node = g * NPG + sel[r];
    float4 f = *(const float4*)&feat[(size_t)node * 256 + c4];
    float4 a = *(const float4*)&cA[c4];
    float4 b = *(const float4*)&cB[c4];
    float tg = gate[r];
    float4 o;
    o.x = fmaf(f.x, a.x, b.x) * tg;
    o.y = fmaf(f.y, a.y, b.y) * tg;
    o.z = fmaf(f.z, a.z, b.z) * tg;
    o.w = fmaf(f.w, a.w, b.w) * tg;
    *(float4*)&out[(size_t)(g * KKEEP + r) * 256 + c4] = o;
  }
}

extern "C" void kernel_launch(void* const* d_in, const int* in_sizes, int n_in,
                              void* d_out, int out_size, void* d_ws, size_t ws_size,
                              hipStream_t stream) {
  const float* x    = (const float*)d_in[0];
  const int*   ei   = (const int*)d_in[1];
  const float* W    = (const float*)d_in[2];
  const float* attS = (const float*)d_in[3];
  const float* attD = (const float*)d_in[4];
  const float* bias = (const float*)d_in[5];
  const float* gam  = (const float*)d_in[6];
  const float* bet  = (const float*)d_in[7];
  const float* pw   = (const float*)d_in[8];
  float* out = (float*)d_out;
  const int E = in_sizes[1] / 2;

  char* p = (char*)d_ws;
  float* h     = (float*)p; p += (size_t)N_NODES * 256 * 4;
  char* region = p;         p += (size_t)N_NODES * 256 * 4;
  unsigned short* xh = (unsigned short*)region;
  unsigned short* xl = (unsigned short*)(region + (size_t)N_NODES * 256 * 2);
  float* feat  = (float*)region;
  float* a_src = (float*)p; p += (size_t)N_NODES * 4 * 4;
  float* a_dst = (float*)p; p += (size_t)N_NODES * 4 * 4;
  float* score = (float*)p; p += (size_t)N_NODES * 4;
  double* psum = (double*)p; p += (size_t)256 * 256 * 8;
  double* psq  = (double*)p; p += (size_t)256 * 256 * 8;
  float* cA    = (float*)p; p += 256 * 4;
  float* cB    = (float*)p; p += 256 * 4;
  float* pwn   = (float*)p; p += 256 * 4;
  unsigned short* wth  = (unsigned short*)p; p += (size_t)256 * 256 * 2;
  unsigned short* wtl  = (unsigned short*)p; p += (size_t)256 * 256 * 2;
  unsigned short* wtll = (unsigned short*)p; p += (size_t)256 * 256 * 2;
  int* cnt     = (int*)p;   p += (size_t)N_NODES * 4;
  unsigned short* nbr = (unsigned short*)p; p += (size_t)N_NODES * CAP * 2;

  hipMemsetAsync(cnt, 0, (size_t)N_NODES * 4, stream);
  k_hist<<<(E + 255) / 256, 256, 0, stream>>>(ei, E, cnt, nbr);
  k_conv<<<2112, 256, 0, stream>>>(x, W, xh, xl, wth, wtl, wtll);
  k_gemm<<<512, 256, 0, stream>>>(x, xh, xl, wth, wtl, wtll, attS, attD, h, a_src, a_dst);
  k_agg<<<N_NODES / 4, 256, 0, stream>>>(h, a_src, a_dst, cnt, nbr, bias, feat);
  k_bn_partial<<<256, 256, 0, stream>>>(feat, psum, psq);
  k_bn_final<<<1, 1024, 0, stream>>>(psum, psq, gam, bet, pw, cA, cB, pwn);
  k_score<<<N_NODES / 4, 256, 0, stream>>>(feat, cA, cB, pwn, score);
  k_topk<<<NGRAPH, 512, 0, stream>>>(score, feat, cA, cB, out);
}